// Round 1
// baseline (811.514 us; speedup 1.0000x reference)
//
#include <hip/hip_runtime.h>
#include <hip/hip_bf16.h>

#define BATCH 32
#define DIM   3072
#define NTRAIN 100000

#define S_CHUNKS 50
#define JPC      2000   /* NTRAIN / S_CHUNKS */
#define DBLK     24     /* DIM / 128 */

typedef __bf16 bf16x8 __attribute__((ext_vector_type(8)));
typedef float  f32x16 __attribute__((ext_vector_type(16)));
typedef unsigned short u16;
typedef unsigned int   u32;

union Frag8 {
    u16    us[8];
    bf16x8 bf;
    uint4  u4;
};

__device__ __forceinline__ u16 bf_trunc(float f) {
    return (u16)(__float_as_uint(f) >> 16);
}
__device__ __forceinline__ float bf_hi_f(float f) {
    return __uint_as_float(__float_as_uint(f) & 0xFFFF0000u);
}

// ---------------- K0: split x into bf16 hi/lo ----------------
__global__ __launch_bounds__(256) void k0_split_x(
        const float* __restrict__ x, u16* __restrict__ xh, u16* __restrict__ xl) {
    int i = blockIdx.x * 256 + threadIdx.x;
    if (i >= BATCH * DIM) return;
    float f  = x[i];
    float hf = bf_hi_f(f);
    xh[i] = bf_trunc(f);
    xl[i] = bf_trunc(f - hf);
}

// ---------------- K1: logits[b][j] = c1*cross - c2*tsq ----------------
// One wave handles 32 j-columns, all 32 b-rows, full K=3072.
// MFMA 32x32x16 bf16, hi/lo split (3 mfma per k-step).
__global__ __launch_bounds__(256) void k1_logits(
        const float* __restrict__ train,
        const u16* __restrict__ xh, const u16* __restrict__ xl,
        const float* __restrict__ alphas, const int* __restrict__ tptr,
        float* __restrict__ logits) {
    float ab = alphas[tptr[0]];
    float s  = sqrtf(ab);
    float om = 1.0f - ab;
    float c1 = s / om;
    float c2 = ab / (2.0f * om);

    int lane = threadIdx.x & 63;
    int wave = threadIdx.x >> 6;
    int lj   = lane & 31;      // A row index (b) AND B col index (j-within-tile)
    int g    = lane >> 5;      // k-group
    int j    = blockIdx.x * 128 + wave * 32 + lj;
    int jc   = j < NTRAIN ? j : (NTRAIN - 1);

    const float* trow  = train + (size_t)jc * DIM;
    const u16* xh_row  = xh + lj * DIM;
    const u16* xl_row  = xl + lj * DIM;

    f32x16 acc;
#pragma unroll
    for (int r = 0; r < 16; ++r) acc[r] = 0.0f;
    float tsq = 0.0f;

    for (int kb = 0; kb < DIM; kb += 16) {
        int ko = kb + 8 * g;
        Frag8 ah, al;
        ah.u4 = *(const uint4*)(xh_row + ko);
        al.u4 = *(const uint4*)(xl_row + ko);
        float4 b0 = *(const float4*)(trow + ko);
        float4 b1 = *(const float4*)(trow + ko + 4);
        float bv[8] = {b0.x, b0.y, b0.z, b0.w, b1.x, b1.y, b1.z, b1.w};
        Frag8 bh, bl;
#pragma unroll
        for (int e = 0; e < 8; ++e) {
            float f = bv[e];
            bh.us[e] = bf_trunc(f);
            float lo = f - bf_hi_f(f);
            bl.us[e] = bf_trunc(lo);
            tsq = fmaf(f, f, tsq);
        }
        acc = __builtin_amdgcn_mfma_f32_32x32x16_bf16(ah.bf, bh.bf, acc, 0, 0, 0);
        acc = __builtin_amdgcn_mfma_f32_32x32x16_bf16(al.bf, bh.bf, acc, 0, 0, 0);
        acc = __builtin_amdgcn_mfma_f32_32x32x16_bf16(ah.bf, bl.bf, acc, 0, 0, 0);
    }
    // full t_sq[j]: the two lane-halves covered disjoint k
    tsq += __shfl_xor(tsq, 32, 64);

    if (j < NTRAIN) {
#pragma unroll
        for (int r = 0; r < 16; ++r) {
            int brow = (r & 3) + 8 * (r >> 2) + 4 * g;   // verified C/D layout
            float lg = c1 * acc[r] - c2 * tsq;
            logits[(size_t)brow * NTRAIN + j] = lg;
        }
    }
}

// ---------------- K2: row max ----------------
__global__ __launch_bounds__(1024) void k2_rowmax(
        const float* __restrict__ logits, float* __restrict__ m) {
    int b = blockIdx.x;
    const float* row = logits + (size_t)b * NTRAIN;
    float mx = -3.0e38f;
    for (int i = threadIdx.x; i < NTRAIN; i += 1024) mx = fmaxf(mx, row[i]);
    __shared__ float red[1024];
    red[threadIdx.x] = mx;
    __syncthreads();
    for (int off = 512; off > 0; off >>= 1) {
        if (threadIdx.x < (unsigned)off)
            red[threadIdx.x] = fmaxf(red[threadIdx.x], red[threadIdx.x + off]);
        __syncthreads();
    }
    if (threadIdx.x == 0) m[b] = red[0];
}

// ---------------- K3: PV partial sums + softmax denominators ----------------
// grid = DBLK * S_CHUNKS blocks; block = 4 waves; wave covers 32 d-cols, 32 b.
__global__ __launch_bounds__(256) void k3_pv(
        const float* __restrict__ train,
        const float* __restrict__ logits,
        const float* __restrict__ m,
        float* __restrict__ partial,   // [S][BATCH][DIM]
        float* __restrict__ psum) {    // [S][BATCH]
    int lane = threadIdx.x & 63;
    int wave = threadIdx.x >> 6;
    int dblk = blockIdx.x % DBLK;
    int s    = blockIdx.x / DBLK;
    int g    = lane >> 5;
    int l31  = lane & 31;
    int dcol = dblk * 128 + wave * 32 + l31;   // B col (d)
    float mb = m[l31];                          // A row (b) = l31

    const float* lrow = logits + (size_t)l31 * NTRAIN;

    f32x16 acc;
#pragma unroll
    for (int r = 0; r < 16; ++r) acc[r] = 0.0f;
    float ps = 0.0f;

    for (int ks = 0; ks < JPC; ks += 16) {
        int jb = s * JPC + ks + 8 * g;
        float4 l0 = *(const float4*)(lrow + jb);
        float4 l1 = *(const float4*)(lrow + jb + 4);
        float lv[8] = {l0.x, l0.y, l0.z, l0.w, l1.x, l1.y, l1.z, l1.w};
        Frag8 aw;
#pragma unroll
        for (int e = 0; e < 8; ++e) {
            float w = __expf(lv[e] - mb);
            u16 wb  = bf_trunc(w);
            aw.us[e] = wb;
            ps += __uint_as_float((u32)wb << 16);
        }
        Frag8 bt;
#pragma unroll
        for (int e = 0; e < 8; ++e) {
            float f = train[(size_t)(jb + e) * DIM + dcol];
            bt.us[e] = bf_trunc(f);
        }
        acc = __builtin_amdgcn_mfma_f32_32x32x16_bf16(aw.bf, bt.bf, acc, 0, 0, 0);
    }

    // denominators: one writer per (s, b)
    ps += __shfl_xor(ps, 32, 64);
    if (dblk == 0 && wave == 0 && lane < 32) psum[s * BATCH + lane] = ps;

#pragma unroll
    for (int r = 0; r < 16; ++r) {
        int brow = (r & 3) + 8 * (r >> 2) + 4 * g;
        partial[((size_t)s * BATCH + brow) * DIM + dcol] = acc[r];
    }
}

// ---------------- K4: reduce partials, scale, output ----------------
__global__ __launch_bounds__(256) void k4_final(
        const float* __restrict__ x,
        const float* __restrict__ partial,
        const float* __restrict__ psum,
        const float* __restrict__ alphas, const int* __restrict__ tptr,
        float* __restrict__ out) {
    int i = blockIdx.x * 256 + threadIdx.x;
    if (i >= BATCH * DIM) return;
    float ab  = alphas[tptr[0]];
    float s   = sqrtf(ab);
    float om  = 1.0f - ab;
    float inv = 1.0f / sqrtf(om);
    int b = i / DIM;
    float l = 0.0f, wsum = 0.0f;
    for (int c = 0; c < S_CHUNKS; ++c) {
        l    += psum[c * BATCH + b];
        wsum += partial[(size_t)c * (BATCH * DIM) + i];
    }
    float weighted = wsum / l;
    out[i] = inv * x[i] - s * inv * weighted;
}

extern "C" void kernel_launch(void* const* d_in, const int* in_sizes, int n_in,
                              void* d_out, int out_size, void* d_ws, size_t ws_size,
                              hipStream_t stream) {
    const float* x      = (const float*)d_in[0];
    const float* train  = (const float*)d_in[1];
    const float* alphas = (const float*)d_in[2];
    const int*   tptr   = (const int*)d_in[3];
    float* out = (float*)d_out;

    char* ws = (char*)d_ws;
    u16*   xh      = (u16*)ws;                                   // 196608 B
    u16*   xl      = (u16*)(ws + 196608);                        // 196608 B
    float* logits  = (float*)(ws + 393216);                      // 12.8 MB
    float* m       = (float*)(ws + 393216 + 12800000);           // 128 B
    float* partial = (float*)(ws + 393216 + 12800000 + 256);     // 19.66 MB
    float* psum    = (float*)(ws + 393216 + 12800000 + 256
                              + (size_t)S_CHUNKS * BATCH * DIM * 4); // 6.4 KB

    k0_split_x<<<(BATCH * DIM + 255) / 256, 256, 0, stream>>>(x, xh, xl);
    k1_logits<<<(NTRAIN + 127) / 128, 256, 0, stream>>>(train, xh, xl, alphas, tptr, logits);
    k2_rowmax<<<BATCH, 1024, 0, stream>>>(logits, m);
    k3_pv<<<DBLK * S_CHUNKS, 256, 0, stream>>>(train, logits, m, partial, psum);
    k4_final<<<(BATCH * DIM + 255) / 256, 256, 0, stream>>>(x, partial, psum, alphas, tptr, out);
}